// Round 1
// 215.781 us; speedup vs baseline: 1.0534x; 1.0534x over previous
//
#include <hip/hip_runtime.h>
#include <stdint.h>

typedef unsigned short u16;
typedef unsigned int   u32;
typedef __bf16 bf16_t;
typedef bf16_t bf16x8 __attribute__((ext_vector_type(8)));
typedef float  f32x4  __attribute__((ext_vector_type(4)));

#define BB 16
#define CC 256
#define NN 4096
#define KK 128

// workspace layout (float offsets into W = (float*)d_ws)
#define OFF_M2B  0        // 32768 f: M2B[d][k] = sum_c w2[d,c]*mk[c,k] (fp32)
#define OFF_BK   32768    // 128 f  : biask[k] = sum_d b1[d]*mk[d,k]
#define OFF_S    32896    // 2048 f : s[b][k] (zeroed by K0)
#define OFF_BN   34944    // 16 replicas * 512 f (zeroed by K0)
#define OFF_SC   43136    // 256 f
#define OFF_SH   43392    // 256 f
#define OFF_RN   43648    // 65536 f: rn[b][n] = 1/(1e-5 + rowsum)
#define WS_F_END 109184
#define OFF_M1P_BYTES  (109184*4)                 // M1P[k][c] bf16, 64 KB
#define OFF_M2S_BYTES  (OFF_M1P_BYTES + 65536)    // M2s[b][d][k] bf16, 1 MB
#define OFF_P_BYTES    (OFF_M2S_BYTES + 1048576)  // p bf16 [B][N][K], 16.78 MB

__device__ __forceinline__ float bf2f(u16 h) {
  union { u32 u; float f; } v; v.u = ((u32)h) << 16; return v.f;
}
__device__ __forceinline__ u16 f2bf(float f) {
  union { float f; u32 u; } v; v.f = f;
  u32 r = (v.u + 0x7FFFu + ((v.u >> 16) & 1u)) >> 16;
  return (u16)r;
}

union BF8 { u16 u[8]; bf16x8 v; };

// ---------------- K0: M1P (bf16 packed), M2B, biask; zero s/bn --------------
__global__ __launch_bounds__(256) void k0_pre(
    const float* __restrict__ w1, const float* __restrict__ b1,
    const float* __restrict__ mk, const float* __restrict__ w2,
    float* __restrict__ W)
{
  u16* M1P = (u16*)((char*)W + OFF_M1P_BYTES);
  int g = blockIdx.x * 256 + threadIdx.x;
  if (g < 32768) {
    int k = g >> 8, c = g & 255;   // M1P[k][c] = sum_d w1[d,c]*mk[d,k]
    float s0 = 0.f, s1 = 0.f, s2 = 0.f, s3 = 0.f;
#pragma unroll 4
    for (int d = 0; d < 256; d += 4) {
      s0 = fmaf(w1[(d+0)*256 + c], mk[(d+0)*128 + k], s0);
      s1 = fmaf(w1[(d+1)*256 + c], mk[(d+1)*128 + k], s1);
      s2 = fmaf(w1[(d+2)*256 + c], mk[(d+2)*128 + k], s2);
      s3 = fmaf(w1[(d+3)*256 + c], mk[(d+3)*128 + k], s3);
    }
    M1P[g] = f2bf((s0 + s1) + (s2 + s3));
  } else if (g < 65536) {
    int g2 = g - 32768;
    int d = g2 >> 7, k = g2 & 127; // M2B[d][k] = sum_c w2[d,c]*mk[c,k]
    float s0 = 0.f, s1 = 0.f, s2 = 0.f, s3 = 0.f;
#pragma unroll 4
    for (int c = 0; c < 256; c += 4) {
      s0 = fmaf(w2[d*256 + c+0], mk[(c+0)*128 + k], s0);
      s1 = fmaf(w2[d*256 + c+1], mk[(c+1)*128 + k], s1);
      s2 = fmaf(w2[d*256 + c+2], mk[(c+2)*128 + k], s2);
      s3 = fmaf(w2[d*256 + c+3], mk[(c+3)*128 + k], s3);
    }
    W[OFF_M2B + g2] = (s0 + s1) + (s2 + s3);
  } else if (g < 65664) {
    int k = g - 65536;
    float s0 = 0.f, s1 = 0.f, s2 = 0.f, s3 = 0.f;
#pragma unroll 4
    for (int d = 0; d < 256; d += 4) {
      s0 = fmaf(b1[d+0], mk[(d+0)*128 + k], s0);
      s1 = fmaf(b1[d+1], mk[(d+1)*128 + k], s1);
      s2 = fmaf(b1[d+2], mk[(d+2)*128 + k], s2);
      s3 = fmaf(b1[d+3], mk[(d+3)*128 + k], s3);
    }
    W[OFF_BK + k] = (s0 + s1) + (s2 + s3);
  } else if (g < 65664 + 10240) {
    W[OFF_S + (g - 65664)] = 0.f;  // zero s[] and bnacc (contiguous)
  }
}

// ---------------- K1: p = exp(x^T @ M1 + biask); s[b][k] = sum_n p ---------
// grid (64 n-tiles, 16 b), block 256 = 4 waves. Wave: 16 tokens x 128 k.
// v2: stage x tile (256c x 64n) in LDS as bf16 via coalesced float4 loads;
//     the c-transpose happens as stride-68 ds_read_u16 (2-way bank = free).
//     Column-sum s[] reduced through LDS (1 global atomic per k per block).
#define XS_STRIDE 68   // 64 + 4 pad (u16): bank = (2c + n/2) % 32 -> 2-way
__global__ __launch_bounds__(256, 4) void k1_logits(
    const float* __restrict__ x, float* __restrict__ W,
    u16* __restrict__ p)
{
  const u16* M1P = (const u16*)((char*)W + OFF_M1P_BYTES);
  const float* biask = W + OFF_BK;
  float* s_glob = W + OFF_S;

  __shared__ u16  xs[256 * XS_STRIDE];   // 34816 B
  __shared__ float s_lds[128];

  const int tid  = threadIdx.x;
  const int wave = tid >> 6;
  const int lane = tid & 63;
  const int q    = lane >> 4;
  const int col  = lane & 15;
  const int b    = blockIdx.y;
  const int n_blk  = blockIdx.x * 64;
  const int n_base = n_blk + wave * 16;

  // ---- stage x[b][0:256][n_blk:n_blk+64] -> LDS bf16 (coalesced 256B rows)
  {
    const float* xb = x + (size_t)b * CC * NN;
#pragma unroll
    for (int it = 0; it < 16; ++it) {
      int g = it * 256 + tid;            // [0, 4096) float4 units
      int c = g >> 4, i4 = (g & 15) * 4;
      float4 v = *(const float4*)(xb + (size_t)c * NN + n_blk + i4);
      ushort4 pk;
      pk.x = f2bf(v.x); pk.y = f2bf(v.y); pk.z = f2bf(v.z); pk.w = f2bf(v.w);
      *(ushort4*)(&xs[c * XS_STRIDE + i4]) = pk;
    }
  }
  if (tid < 128) s_lds[tid] = 0.f;
  __syncthreads();

  f32x4 acc[8];
#pragma unroll
  for (int t = 0; t < 8; ++t) acc[t] = (f32x4){0.f, 0.f, 0.f, 0.f};

  const int wn = wave * 16;
  for (int c0 = 0; c0 < 256; c0 += 32) {
    BF8 af;
#pragma unroll
    for (int j = 0; j < 8; ++j)
      af.u[j] = xs[(c0 + q * 8 + j) * XS_STRIDE + wn + col];
#pragma unroll
    for (int t = 0; t < 8; ++t) {
      bf16x8 bf = *(const bf16x8*)(M1P + (t*16 + col) * 256 + c0 + q*8);
      acc[t] = __builtin_amdgcn_mfma_f32_16x16x32_bf16(af.v, bf, acc[t], 0, 0, 0);
    }
  }

  // epilogue: bias, exp, bf16 store, per-k wave reduction -> LDS -> 1 atomic
  u16* pb = p + (size_t)b * NN * KK;
#pragma unroll
  for (int t = 0; t < 8; ++t) {
    const float bk = biask[t*16 + col];
    float ps = 0.f;
#pragma unroll
    for (int r = 0; r < 4; ++r) {
      const int n = n_base + q*4 + r;
      float e = __expf(acc[t][r] + bk);
      u16 hb = f2bf(e);
      pb[(size_t)n * KK + t*16 + col] = hb;
      ps += bf2f(hb);   // accumulate the rounded value for consistency
    }
    ps += __shfl_xor(ps, 16);
    ps += __shfl_xor(ps, 32);
    if (lane < 16) atomicAdd(&s_lds[t*16 + col], ps);
  }
  __syncthreads();
  if (tid < 128) atomicAdd(&s_glob[b*128 + tid], s_lds[tid]);
}

// ---------------- K2: M2s[b][d][k] = M2B/s (bf16); rn[b][n] ----------------
// blocks [0,2048): M2s pack. blocks [2048,3072): rn rowsums (coalesced).
__global__ __launch_bounds__(256) void k2_prep(
    const u16* __restrict__ p, float* __restrict__ W)
{
  __shared__ float sinv[128];
  u16* M2s = (u16*)((char*)W + OFF_M2S_BYTES);
  const float* s_glob = W + OFF_S;
  const int tid = threadIdx.x;

  if (blockIdx.x < 2048) {
    int g = blockIdx.x * 256 + tid;       // [0, 524288)
    int b = g >> 15;
    if (tid < 128) sinv[tid] = 1.0f / s_glob[b*128 + tid];
    __syncthreads();
    int rem = g & 32767;                  // d*128 + k
    M2s[g] = f2bf(W[OFF_M2B + rem] * sinv[g & 127]);
  } else {
    int nb = blockIdx.x - 2048;           // [0, 1024)
    int b  = nb >> 6;
    int n0 = (nb & 63) * 64;
    if (tid < 128) sinv[tid] = 1.0f / s_glob[b*128 + tid];
    __syncthreads();
    const int tx = tid & 3;               // k-quarter (32 k)
    const int ty = tid >> 2;              // token within tile (0..63)
    const int n  = n0 + ty;
    const u16* pr = p + ((size_t)b * NN + n) * KK + tx * 32;
    float t = 0.f;
#pragma unroll
    for (int j = 0; j < 4; ++j) {
      uint4 v = *(const uint4*)(pr + j*8);
      const int k8 = tx*32 + j*8;
      t += bf2f((u16)(v.x & 0xffff)) * sinv[k8+0];
      t += bf2f((u16)(v.x >> 16))    * sinv[k8+1];
      t += bf2f((u16)(v.y & 0xffff)) * sinv[k8+2];
      t += bf2f((u16)(v.y >> 16))    * sinv[k8+3];
      t += bf2f((u16)(v.z & 0xffff)) * sinv[k8+4];
      t += bf2f((u16)(v.z >> 16))    * sinv[k8+5];
      t += bf2f((u16)(v.w & 0xffff)) * sinv[k8+6];
      t += bf2f((u16)(v.w >> 16))    * sinv[k8+7];
    }
    t += __shfl_xor(t, 1);
    t += __shfl_xor(t, 2);
    if (tx == 0) W[OFF_RN + b*4096 + n] = 1.0f / (1e-5f + t);
  }
}

// ---------------- K3: o3 = (p @ M2s^T)*rn + b2 ; BN partials ---------------
// grid (64 n-tiles, 16 b), block 256 = 4 waves. Wave: 64 tokens x 64 d
// (4 token-groups x 4 d-tiles) -> loads:MFMA = 1:4, am slice 16KB (L1-fit).
__global__ __launch_bounds__(256, 4) void k3_attn(
    const u16* __restrict__ p, const float* __restrict__ b2,
    float* __restrict__ W, float* __restrict__ o3)
{
  const u16* M2s = (const u16*)((char*)W + OFF_M2S_BYTES);
  const float* rn = W + OFF_RN;
  float* bnacc = W + OFF_BN;

  const int tid  = threadIdx.x;
  const int wave = tid >> 6;
  const int lane = tid & 63;
  const int q    = lane >> 4;
  const int col  = lane & 15;
  const int b    = blockIdx.y;
  const int n_base = blockIdx.x * 64;
  const int d_base = wave * 64;

  f32x4 acc[4][4];
#pragma unroll
  for (int g = 0; g < 4; ++g)
#pragma unroll
    for (int t = 0; t < 4; ++t) acc[g][t] = (f32x4){0.f, 0.f, 0.f, 0.f};

  const u16* pb0 = p + ((size_t)b * NN + n_base + col) * KK;
  const u16* m2b = M2s + ((size_t)b << 15) + (size_t)(d_base + col) * 128;

#pragma unroll
  for (int k0 = 0; k0 < 128; k0 += 32) {
    bf16x8 bfp[4], amv[4];
#pragma unroll
    for (int g = 0; g < 4; ++g)
      bfp[g] = *(const bf16x8*)(pb0 + (size_t)(g*16)*KK + k0 + q*8);
#pragma unroll
    for (int t = 0; t < 4; ++t)
      amv[t] = *(const bf16x8*)(m2b + (size_t)(t*16)*128 + k0 + q*8);
#pragma unroll
    for (int g = 0; g < 4; ++g)
#pragma unroll
      for (int t = 0; t < 4; ++t)
        // A = p (m=token), B = M2s (n=d): D row=token, col=d
        acc[g][t] = __builtin_amdgcn_mfma_f32_16x16x32_bf16(bfp[g], amv[t], acc[g][t], 0, 0, 0);
  }

  // epilogue: *rn + b2, float4 token-contiguous stores, register-folded BN
  float* ob = o3 + (size_t)b * CC * NN;
  float s1t[4] = {0.f, 0.f, 0.f, 0.f};
  float s2t[4] = {0.f, 0.f, 0.f, 0.f};
#pragma unroll
  for (int g = 0; g < 4; ++g) {
    const float4 rn4 = *(const float4*)(rn + b*4096 + n_base + g*16 + q*4);
#pragma unroll
    for (int t = 0; t < 4; ++t) {
      const int d = d_base + t*16 + col;
      const float bb = b2[d];
      float4 vv;
      vv.x = fmaf(acc[g][t][0], rn4.x, bb);
      vv.y = fmaf(acc[g][t][1], rn4.y, bb);
      vv.z = fmaf(acc[g][t][2], rn4.z, bb);
      vv.w = fmaf(acc[g][t][3], rn4.w, bb);
      *(float4*)(ob + (size_t)d * NN + n_base + g*16 + q*4) = vv;
      s1t[t] += vv.x + vv.y + vv.z + vv.w;
      s2t[t] += vv.x*vv.x + vv.y*vv.y + vv.z*vv.z + vv.w*vv.w;
    }
  }
  const int rep = blockIdx.x & 15;
#pragma unroll
  for (int t = 0; t < 4; ++t) {
    float s1 = s1t[t], s2 = s2t[t];
    s1 += __shfl_xor(s1, 16);  s2 += __shfl_xor(s2, 16);
    s1 += __shfl_xor(s1, 32);  s2 += __shfl_xor(s2, 32);
    if (lane < 16) {
      const int d = d_base + t*16 + col;
      atomicAdd(&bnacc[rep*512 + d], s1);
      atomicAdd(&bnacc[rep*512 + 256 + d], s2);
    }
  }
}

// ---------------- K4: finalize BN scale/shift ------------------------------
__global__ __launch_bounds__(256) void k4_fin(
    const float* __restrict__ gamma, const float* __restrict__ beta,
    float* __restrict__ W)
{
  const float* bnacc = W + OFF_BN;
  int d = threadIdx.x;
  float s1 = 0.f, s2 = 0.f;
#pragma unroll
  for (int r = 0; r < 16; ++r) { s1 += bnacc[r*512 + d]; s2 += bnacc[r*512 + 256 + d]; }
  const float invn = 1.0f / 65536.0f;
  float mean = s1 * invn;
  float var = s2 * invn - mean * mean;
  float sc = gamma[d] * rsqrtf(var + 1e-3f);
  W[OFF_SC + d] = sc;
  W[OFF_SH + d] = beta[d] - mean * sc;
}

// ---------------- K5: BN apply + residual + LeakyReLU (in-place on d_out) --
__global__ __launch_bounds__(256) void k5_out(
    const float* __restrict__ x, const float* __restrict__ W,
    float* __restrict__ out)
{
  const float* scale = W + OFF_SC;
  const float* shift = W + OFF_SH;
  size_t gid = ((size_t)blockIdx.x * 256 + threadIdx.x) * 4;
  const int d = (int)((gid >> 12) & 255);
  const float sc = scale[d], sh = shift[d];
  float4 o = *(const float4*)(out + gid);     // o3 stored in d_out (fp32)
  float4 xv = *(const float4*)(x + gid);
  float v0 = fmaf(o.x, sc, sh) + xv.x;
  float v1 = fmaf(o.y, sc, sh) + xv.y;
  float v2 = fmaf(o.z, sc, sh) + xv.z;
  float v3 = fmaf(o.w, sc, sh) + xv.w;
  v0 = (v0 >= 0.f) ? v0 : 0.2f * v0;
  v1 = (v1 >= 0.f) ? v1 : 0.2f * v1;
  v2 = (v2 >= 0.f) ? v2 : 0.2f * v2;
  v3 = (v3 >= 0.f) ? v3 : 0.2f * v3;
  float4 st; st.x = v0; st.y = v1; st.z = v2; st.w = v3;
  *(float4*)(out + gid) = st;
}

extern "C" void kernel_launch(void* const* d_in, const int* in_sizes, int n_in,
                              void* d_out, int out_size, void* d_ws, size_t ws_size,
                              hipStream_t stream)
{
  const float* x  = (const float*)d_in[0];
  const float* w1 = (const float*)d_in[1];
  const float* b1 = (const float*)d_in[2];
  const float* mk = (const float*)d_in[3];
  const float* w2 = (const float*)d_in[4];
  const float* b2 = (const float*)d_in[5];
  const float* gamma = (const float*)d_in[6];
  const float* beta  = (const float*)d_in[7];

  float* W = (float*)d_ws;
  u16* p = (u16*)((char*)d_ws + OFF_P_BYTES);  // exp(logits) bf16 [B][N][K]
  float* o3 = (float*)d_out;   // fp32 [B][C][N] in d_out until K5 rewrites in place
  float* out = (float*)d_out;

  k0_pre<<<dim3(297), dim3(256), 0, stream>>>(w1, b1, mk, w2, W);
  k1_logits<<<dim3(64, 16), dim3(256), 0, stream>>>(x, W, p);
  k2_prep<<<dim3(3072), dim3(256), 0, stream>>>(p, W);
  k3_attn<<<dim3(64, 16), dim3(256), 0, stream>>>(p, b2, W, o3);
  k4_fin<<<dim3(1), dim3(256), 0, stream>>>(gamma, beta, W);
  k5_out<<<dim3(16384), dim3(256), 0, stream>>>(x, W, out);
}

// Round 3
// 212.170 us; speedup vs baseline: 1.0713x; 1.0170x over previous
//
#include <hip/hip_runtime.h>
#include <stdint.h>

typedef unsigned short u16;
typedef unsigned int   u32;
typedef __bf16 bf16_t;
typedef bf16_t bf16x8 __attribute__((ext_vector_type(8)));
typedef float  f32x4  __attribute__((ext_vector_type(4)));

#define BB 16
#define CC 256
#define NN 4096
#define KK 128

// workspace layout (float offsets into W = (float*)d_ws)
#define OFF_M2B  0        // 32768 f: M2B[d][k] = sum_c w2[d,c]*mk[c,k] (fp32)
#define OFF_BK   32768    // 128 f  : biask[k] = sum_d b1[d]*mk[d,k]
#define OFF_S    32896    // 2048 f : s[b][k] (zeroed by K0)
#define OFF_BN   34944    // 16 replicas * 512 f (zeroed by K0)
#define OFF_SC   43136    // 256 f
#define OFF_SH   43392    // 256 f
#define OFF_RN   43648    // 65536 f: rn[b][n] = 1/(1e-5 + rowsum)
#define WS_F_END 109184
#define OFF_M1P_BYTES  (109184*4)                 // M1P[k][c] bf16, 64 KB
#define OFF_M2S_BYTES  (OFF_M1P_BYTES + 65536)    // M2s[b][d][k] bf16, 1 MB
#define OFF_P_BYTES    (OFF_M2S_BYTES + 1048576)  // p bf16 [B][N][K], 16.78 MB
#define OFF_O3B_BYTES  (OFF_P_BYTES + 16777216)   // o3 bf16 [B][C][N], 33.55 MB (optional)
#define WS_NEED_BF16   (OFF_O3B_BYTES + 33554432ull)

__device__ __forceinline__ float bf2f(u16 h) {
  union { u32 u; float f; } v; v.u = ((u32)h) << 16; return v.f;
}
__device__ __forceinline__ u16 f2bf(float f) {
  union { float f; u32 u; } v; v.f = f;
  u32 r = (v.u + 0x7FFFu + ((v.u >> 16) & 1u)) >> 16;
  return (u16)r;
}

union BF8 { u16 u[8]; bf16x8 v; };

// ---------------- K0: M1P (bf16 packed), M2B, biask; zero s/bn --------------
__global__ __launch_bounds__(256) void k0_pre(
    const float* __restrict__ w1, const float* __restrict__ b1,
    const float* __restrict__ mk, const float* __restrict__ w2,
    float* __restrict__ W)
{
  u16* M1P = (u16*)((char*)W + OFF_M1P_BYTES);
  int g = blockIdx.x * 256 + threadIdx.x;
  if (g < 32768) {
    int k = g >> 8, c = g & 255;   // M1P[k][c] = sum_d w1[d,c]*mk[d,k]
    float s0 = 0.f, s1 = 0.f, s2 = 0.f, s3 = 0.f;
#pragma unroll 4
    for (int d = 0; d < 256; d += 4) {
      s0 = fmaf(w1[(d+0)*256 + c], mk[(d+0)*128 + k], s0);
      s1 = fmaf(w1[(d+1)*256 + c], mk[(d+1)*128 + k], s1);
      s2 = fmaf(w1[(d+2)*256 + c], mk[(d+2)*128 + k], s2);
      s3 = fmaf(w1[(d+3)*256 + c], mk[(d+3)*128 + k], s3);
    }
    M1P[g] = f2bf((s0 + s1) + (s2 + s3));
  } else if (g < 65536) {
    int g2 = g - 32768;
    int d = g2 >> 7, k = g2 & 127; // M2B[d][k] = sum_c w2[d,c]*mk[c,k]
    float s0 = 0.f, s1 = 0.f, s2 = 0.f, s3 = 0.f;
#pragma unroll 4
    for (int c = 0; c < 256; c += 4) {
      s0 = fmaf(w2[d*256 + c+0], mk[(c+0)*128 + k], s0);
      s1 = fmaf(w2[d*256 + c+1], mk[(c+1)*128 + k], s1);
      s2 = fmaf(w2[d*256 + c+2], mk[(c+2)*128 + k], s2);
      s3 = fmaf(w2[d*256 + c+3], mk[(c+3)*128 + k], s3);
    }
    W[OFF_M2B + g2] = (s0 + s1) + (s2 + s3);
  } else if (g < 65664) {
    int k = g - 65536;
    float s0 = 0.f, s1 = 0.f, s2 = 0.f, s3 = 0.f;
#pragma unroll 4
    for (int d = 0; d < 256; d += 4) {
      s0 = fmaf(b1[d+0], mk[(d+0)*128 + k], s0);
      s1 = fmaf(b1[d+1], mk[(d+1)*128 + k], s1);
      s2 = fmaf(b1[d+2], mk[(d+2)*128 + k], s2);
      s3 = fmaf(b1[d+3], mk[(d+3)*128 + k], s3);
    }
    W[OFF_BK + k] = (s0 + s1) + (s2 + s3);
  } else if (g < 65664 + 10240) {
    W[OFF_S + (g - 65664)] = 0.f;  // zero s[] and bnacc (contiguous)
  }
}

// ---------------- K1: p = exp(x^T @ M1 + biask); s[b][k] = sum_n p ---------
// grid (64 n-tiles, 16 b), block 256 = 4 waves. Wave: 16 tokens x 128 k.
// v3: c0 loop fully unrolled + loads batched before MFMAs so the scheduler
//     can pipeline ~2 iterations of M1P loads (L2 ~200cy) under the MFMAs.
#define XS_STRIDE 68   // 64 + 4 pad (u16): bank = (2c + n/2) % 32 -> 2-way
__global__ __launch_bounds__(256, 4) void k1_logits(
    const float* __restrict__ x, float* __restrict__ W,
    u16* __restrict__ p)
{
  const u16* M1P = (const u16*)((char*)W + OFF_M1P_BYTES);
  const float* biask = W + OFF_BK;
  float* s_glob = W + OFF_S;

  __shared__ u16  xs[256 * XS_STRIDE];   // 34816 B
  __shared__ float s_lds[128];

  const int tid  = threadIdx.x;
  const int wave = tid >> 6;
  const int lane = tid & 63;
  const int q    = lane >> 4;
  const int col  = lane & 15;
  const int b    = blockIdx.y;
  const int n_blk  = blockIdx.x * 64;
  const int n_base = n_blk + wave * 16;

  // ---- stage x[b][0:256][n_blk:n_blk+64] -> LDS bf16 (coalesced 256B rows)
  {
    const float* xb = x + (size_t)b * CC * NN;
#pragma unroll
    for (int it = 0; it < 16; ++it) {
      int g = it * 256 + tid;            // [0, 4096) float4 units
      int c = g >> 4, i4 = (g & 15) * 4;
      float4 v = *(const float4*)(xb + (size_t)c * NN + n_blk + i4);
      ushort4 pk;
      pk.x = f2bf(v.x); pk.y = f2bf(v.y); pk.z = f2bf(v.z); pk.w = f2bf(v.w);
      *(ushort4*)(&xs[c * XS_STRIDE + i4]) = pk;
    }
  }
  if (tid < 128) s_lds[tid] = 0.f;
  __syncthreads();

  f32x4 acc[8];
#pragma unroll
  for (int t = 0; t < 8; ++t) acc[t] = (f32x4){0.f, 0.f, 0.f, 0.f};

  const int wn = wave * 16;
  const u16* m1l = M1P + col * 256 + q * 8;   // lane-invariant part hoisted
#pragma unroll
  for (int c0 = 0; c0 < 256; c0 += 32) {
    BF8 af;
#pragma unroll
    for (int j = 0; j < 8; ++j)
      af.u[j] = xs[(c0 + q * 8 + j) * XS_STRIDE + wn + col];
    bf16x8 bfv[8];
#pragma unroll
    for (int t = 0; t < 8; ++t)
      bfv[t] = *(const bf16x8*)(m1l + t * 16 * 256 + c0);
#pragma unroll
    for (int t = 0; t < 8; ++t)
      acc[t] = __builtin_amdgcn_mfma_f32_16x16x32_bf16(af.v, bfv[t], acc[t], 0, 0, 0);
  }

  // epilogue: bias, exp, bf16 store, per-k wave reduction -> LDS -> 1 atomic
  u16* pb = p + (size_t)b * NN * KK;
#pragma unroll
  for (int t = 0; t < 8; ++t) {
    const float bk = biask[t*16 + col];
    float ps = 0.f;
#pragma unroll
    for (int r = 0; r < 4; ++r) {
      const int n = n_base + q*4 + r;
      float e = __expf(acc[t][r] + bk);
      u16 hb = f2bf(e);
      pb[(size_t)n * KK + t*16 + col] = hb;
      ps += bf2f(hb);   // accumulate the rounded value for consistency
    }
    ps += __shfl_xor(ps, 16);
    ps += __shfl_xor(ps, 32);
    if (lane < 16) atomicAdd(&s_lds[t*16 + col], ps);
  }
  __syncthreads();
  if (tid < 128) atomicAdd(&s_glob[b*128 + tid], s_lds[tid]);
}

// ---------------- K2: M2s[b][d][k] = M2B/s (bf16); rn[b][n] ----------------
// blocks [0,2048): M2s pack. blocks [2048,3072): rn rowsums (coalesced).
__global__ __launch_bounds__(256) void k2_prep(
    const u16* __restrict__ p, float* __restrict__ W)
{
  __shared__ float sinv[128];
  u16* M2s = (u16*)((char*)W + OFF_M2S_BYTES);
  const float* s_glob = W + OFF_S;
  const int tid = threadIdx.x;

  if (blockIdx.x < 2048) {
    int g = blockIdx.x * 256 + tid;       // [0, 524288)
    int b = g >> 15;
    if (tid < 128) sinv[tid] = 1.0f / s_glob[b*128 + tid];
    __syncthreads();
    int rem = g & 32767;                  // d*128 + k
    M2s[g] = f2bf(W[OFF_M2B + rem] * sinv[g & 127]);
  } else {
    int nb = blockIdx.x - 2048;           // [0, 1024)
    int b  = nb >> 6;
    int n0 = (nb & 63) * 64;
    if (tid < 128) sinv[tid] = 1.0f / s_glob[b*128 + tid];
    __syncthreads();
    const int tx = tid & 3;               // k-quarter (32 k)
    const int ty = tid >> 2;              // token within tile (0..63)
    const int n  = n0 + ty;
    const u16* pr = p + ((size_t)b * NN + n) * KK + tx * 32;
    float t = 0.f;
#pragma unroll
    for (int j = 0; j < 4; ++j) {
      uint4 v = *(const uint4*)(pr + j*8);
      const int k8 = tx*32 + j*8;
      t += bf2f((u16)(v.x & 0xffff)) * sinv[k8+0];
      t += bf2f((u16)(v.x >> 16))    * sinv[k8+1];
      t += bf2f((u16)(v.y & 0xffff)) * sinv[k8+2];
      t += bf2f((u16)(v.y >> 16))    * sinv[k8+3];
      t += bf2f((u16)(v.z & 0xffff)) * sinv[k8+4];
      t += bf2f((u16)(v.z >> 16))    * sinv[k8+5];
      t += bf2f((u16)(v.w & 0xffff)) * sinv[k8+6];
      t += bf2f((u16)(v.w >> 16))    * sinv[k8+7];
    }
    t += __shfl_xor(t, 1);
    t += __shfl_xor(t, 2);
    if (tx == 0) W[OFF_RN + b*4096 + n] = 1.0f / (1e-5f + t);
  }
}

// ---------------- K3: o3 = (p @ M2s^T)*rn + b2 ; BN partials ---------------
// grid (64 n-tiles, 16 b), block 256 = 4 waves. Wave: 64 tokens x 64 d.
// O3BF=true: store o3 as bf16 into workspace (halves store traffic).
template <bool O3BF>
__global__ __launch_bounds__(256, 4) void k3_attn(
    const u16* __restrict__ p, const float* __restrict__ b2,
    float* __restrict__ W, float* __restrict__ o3f, u16* __restrict__ o3b)
{
  const u16* M2s = (const u16*)((char*)W + OFF_M2S_BYTES);
  const float* rn = W + OFF_RN;
  float* bnacc = W + OFF_BN;

  const int tid  = threadIdx.x;
  const int wave = tid >> 6;
  const int lane = tid & 63;
  const int q    = lane >> 4;
  const int col  = lane & 15;
  const int b    = blockIdx.y;
  const int n_base = blockIdx.x * 64;
  const int d_base = wave * 64;

  f32x4 acc[4][4];
#pragma unroll
  for (int g = 0; g < 4; ++g)
#pragma unroll
    for (int t = 0; t < 4; ++t) acc[g][t] = (f32x4){0.f, 0.f, 0.f, 0.f};

  const u16* pb0 = p + ((size_t)b * NN + n_base + col) * KK;
  const u16* m2b = M2s + ((size_t)b << 15) + (size_t)(d_base + col) * 128;

#pragma unroll
  for (int k0 = 0; k0 < 128; k0 += 32) {
    bf16x8 bfp[4], amv[4];
#pragma unroll
    for (int g = 0; g < 4; ++g)
      bfp[g] = *(const bf16x8*)(pb0 + (size_t)(g*16)*KK + k0 + q*8);
#pragma unroll
    for (int t = 0; t < 4; ++t)
      amv[t] = *(const bf16x8*)(m2b + (size_t)(t*16)*128 + k0 + q*8);
#pragma unroll
    for (int g = 0; g < 4; ++g)
#pragma unroll
      for (int t = 0; t < 4; ++t)
        // A = p (m=token), B = M2s (n=d): D row=token, col=d
        acc[g][t] = __builtin_amdgcn_mfma_f32_16x16x32_bf16(bfp[g], amv[t], acc[g][t], 0, 0, 0);
  }

  // epilogue: *rn + b2, token-contiguous stores, register-folded BN
  float* obf = o3f + (size_t)b * CC * NN;
  u16*   obb = o3b + (size_t)b * CC * NN;
  float s1t[4] = {0.f, 0.f, 0.f, 0.f};
  float s2t[4] = {0.f, 0.f, 0.f, 0.f};
#pragma unroll
  for (int g = 0; g < 4; ++g) {
    const float4 rn4 = *(const float4*)(rn + b*4096 + n_base + g*16 + q*4);
#pragma unroll
    for (int t = 0; t < 4; ++t) {
      const int d = d_base + t*16 + col;
      const float bb = b2[d];
      float4 vv;
      vv.x = fmaf(acc[g][t][0], rn4.x, bb);
      vv.y = fmaf(acc[g][t][1], rn4.y, bb);
      vv.z = fmaf(acc[g][t][2], rn4.z, bb);
      vv.w = fmaf(acc[g][t][3], rn4.w, bb);
      if (O3BF) {
        ushort4 pk;
        pk.x = f2bf(vv.x); pk.y = f2bf(vv.y); pk.z = f2bf(vv.z); pk.w = f2bf(vv.w);
        *(ushort4*)(obb + (size_t)d * NN + n_base + g*16 + q*4) = pk;
      } else {
        *(float4*)(obf + (size_t)d * NN + n_base + g*16 + q*4) = vv;
      }
      s1t[t] += vv.x + vv.y + vv.z + vv.w;
      s2t[t] += vv.x*vv.x + vv.y*vv.y + vv.z*vv.z + vv.w*vv.w;
    }
  }
  const int rep = blockIdx.x & 15;
#pragma unroll
  for (int t = 0; t < 4; ++t) {
    float s1 = s1t[t], s2 = s2t[t];
    s1 += __shfl_xor(s1, 16);  s2 += __shfl_xor(s2, 16);
    s1 += __shfl_xor(s1, 32);  s2 += __shfl_xor(s2, 32);
    if (lane < 16) {
      const int d = d_base + t*16 + col;
      atomicAdd(&bnacc[rep*512 + d], s1);
      atomicAdd(&bnacc[rep*512 + 256 + d], s2);
    }
  }
}

// ---------------- K4: finalize BN scale/shift ------------------------------
__global__ __launch_bounds__(256) void k4_fin(
    const float* __restrict__ gamma, const float* __restrict__ beta,
    float* __restrict__ W)
{
  const float* bnacc = W + OFF_BN;
  int d = threadIdx.x;
  float s1 = 0.f, s2 = 0.f;
#pragma unroll
  for (int r = 0; r < 16; ++r) { s1 += bnacc[r*512 + d]; s2 += bnacc[r*512 + 256 + d]; }
  const float invn = 1.0f / 65536.0f;
  float mean = s1 * invn;
  float var = s2 * invn - mean * mean;
  float sc = gamma[d] * rsqrtf(var + 1e-3f);
  W[OFF_SC + d] = sc;
  W[OFF_SH + d] = beta[d] - mean * sc;
}

// ---------------- K5 (fp32 o3 in d_out, in-place): BN+residual+LeakyReLU ---
__global__ __launch_bounds__(256) void k5_out_f32(
    const float* __restrict__ x, const float* __restrict__ W,
    float* __restrict__ out)
{
  const float* scale = W + OFF_SC;
  const float* shift = W + OFF_SH;
  size_t gid = ((size_t)blockIdx.x * 256 + threadIdx.x) * 4;
  const int d = (int)((gid >> 12) & 255);
  const float sc = scale[d], sh = shift[d];
  float4 o = *(const float4*)(out + gid);     // o3 stored in d_out (fp32)
  float4 xv = *(const float4*)(x + gid);
  float v0 = fmaf(o.x, sc, sh) + xv.x;
  float v1 = fmaf(o.y, sc, sh) + xv.y;
  float v2 = fmaf(o.z, sc, sh) + xv.z;
  float v3 = fmaf(o.w, sc, sh) + xv.w;
  v0 = (v0 >= 0.f) ? v0 : 0.2f * v0;
  v1 = (v1 >= 0.f) ? v1 : 0.2f * v1;
  v2 = (v2 >= 0.f) ? v2 : 0.2f * v2;
  v3 = (v3 >= 0.f) ? v3 : 0.2f * v3;
  float4 st; st.x = v0; st.y = v1; st.z = v2; st.w = v3;
  *(float4*)(out + gid) = st;
}

// ---------------- K5 (bf16 o3 in workspace): BN+residual+LeakyReLU ---------
// 8 elements/thread: uint4 bf16 read + 2x float4 x read + 2x float4 write.
__global__ __launch_bounds__(256) void k5_out_bf16(
    const float* __restrict__ x, const float* __restrict__ W,
    const u16* __restrict__ o3b, float* __restrict__ out)
{
  const float* scale = W + OFF_SC;
  const float* shift = W + OFF_SH;
  size_t gid = ((size_t)blockIdx.x * 256 + threadIdx.x) * 8;
  const int d = (int)((gid >> 12) & 255);
  const float sc = scale[d], sh = shift[d];
  uint4 ov = *(const uint4*)(o3b + gid);
  float4 xa = *(const float4*)(x + gid);
  float4 xb = *(const float4*)(x + gid + 4);
  float o0 = bf2f((u16)(ov.x & 0xffff)), o1 = bf2f((u16)(ov.x >> 16));
  float o2 = bf2f((u16)(ov.y & 0xffff)), o3 = bf2f((u16)(ov.y >> 16));
  float o4 = bf2f((u16)(ov.z & 0xffff)), o5 = bf2f((u16)(ov.z >> 16));
  float o6 = bf2f((u16)(ov.w & 0xffff)), o7 = bf2f((u16)(ov.w >> 16));
  float v0 = fmaf(o0, sc, sh) + xa.x;
  float v1 = fmaf(o1, sc, sh) + xa.y;
  float v2 = fmaf(o2, sc, sh) + xa.z;
  float v3 = fmaf(o3, sc, sh) + xa.w;
  float v4 = fmaf(o4, sc, sh) + xb.x;
  float v5 = fmaf(o5, sc, sh) + xb.y;
  float v6 = fmaf(o6, sc, sh) + xb.z;
  float v7 = fmaf(o7, sc, sh) + xb.w;
  v0 = (v0 >= 0.f) ? v0 : 0.2f * v0;
  v1 = (v1 >= 0.f) ? v1 : 0.2f * v1;
  v2 = (v2 >= 0.f) ? v2 : 0.2f * v2;
  v3 = (v3 >= 0.f) ? v3 : 0.2f * v3;
  v4 = (v4 >= 0.f) ? v4 : 0.2f * v4;
  v5 = (v5 >= 0.f) ? v5 : 0.2f * v5;
  v6 = (v6 >= 0.f) ? v6 : 0.2f * v6;
  v7 = (v7 >= 0.f) ? v7 : 0.2f * v7;
  float4 sa; sa.x = v0; sa.y = v1; sa.z = v2; sa.w = v3;
  float4 sb; sb.x = v4; sb.y = v5; sb.z = v6; sb.w = v7;
  *(float4*)(out + gid)     = sa;
  *(float4*)(out + gid + 4) = sb;
}

extern "C" void kernel_launch(void* const* d_in, const int* in_sizes, int n_in,
                              void* d_out, int out_size, void* d_ws, size_t ws_size,
                              hipStream_t stream)
{
  const float* x  = (const float*)d_in[0];
  const float* w1 = (const float*)d_in[1];
  const float* b1 = (const float*)d_in[2];
  const float* mk = (const float*)d_in[3];
  const float* w2 = (const float*)d_in[4];
  const float* b2 = (const float*)d_in[5];
  const float* gamma = (const float*)d_in[6];
  const float* beta  = (const float*)d_in[7];

  float* W = (float*)d_ws;
  u16* p = (u16*)((char*)d_ws + OFF_P_BYTES);  // exp(logits) bf16 [B][N][K]
  u16* o3b = (u16*)((char*)d_ws + OFF_O3B_BYTES);
  float* out = (float*)d_out;
  const bool bigws = ws_size >= WS_NEED_BF16;

  k0_pre<<<dim3(297), dim3(256), 0, stream>>>(w1, b1, mk, w2, W);
  k1_logits<<<dim3(64, 16), dim3(256), 0, stream>>>(x, W, p);
  k2_prep<<<dim3(3072), dim3(256), 0, stream>>>(p, W);
  if (bigws) {
    k3_attn<true><<<dim3(64, 16), dim3(256), 0, stream>>>(p, b2, W, out, o3b);
    k4_fin<<<dim3(1), dim3(256), 0, stream>>>(gamma, beta, W);
    k5_out_bf16<<<dim3(8192), dim3(256), 0, stream>>>(x, W, o3b, out);
  } else {
    k3_attn<false><<<dim3(64, 16), dim3(256), 0, stream>>>(p, b2, W, out, o3b);
    k4_fin<<<dim3(1), dim3(256), 0, stream>>>(gamma, beta, W);
    k5_out_f32<<<dim3(16384), dim3(256), 0, stream>>>(x, W, out);
  }
}

// Round 4
// 208.330 us; speedup vs baseline: 1.0911x; 1.0184x over previous
//
#include <hip/hip_runtime.h>
#include <stdint.h>

typedef unsigned short u16;
typedef unsigned int   u32;
typedef __bf16 bf16_t;
typedef bf16_t bf16x8 __attribute__((ext_vector_type(8)));
typedef float  f32x4  __attribute__((ext_vector_type(4)));

#define BB 16
#define CC 256
#define NN 4096
#define KK 128

// workspace layout (float offsets into W = (float*)d_ws)
#define OFF_M2B  0        // 32768 f: M2B[d][k] = sum_c w2[d,c]*mk[c,k] (fp32)
#define OFF_BK   32768    // 128 f  : biask[k] = sum_d b1[d]*mk[d,k]
#define OFF_S    32896    // 2048 f : s[b][k] (zeroed by K0)
#define OFF_BN   34944    // 16 replicas * 512 f (zeroed by K0)
#define OFF_SC   43136    // 256 f
#define OFF_SH   43392    // 256 f
#define OFF_RN   43648    // 65536 f: (unused since r4 — rn fused into k3)
#define WS_F_END 109184
#define OFF_M1P_BYTES  (109184*4)                 // M1P[k][c] bf16, 64 KB
#define OFF_M2S_BYTES  (OFF_M1P_BYTES + 65536)    // M2s[b][d][k] bf16, 1 MB
#define OFF_P_BYTES    (OFF_M2S_BYTES + 1048576)  // p bf16 [B][N][K], 16.78 MB
#define OFF_O3B_BYTES  (OFF_P_BYTES + 16777216)   // o3 bf16 [B][C][N], 33.55 MB (optional)
#define WS_NEED_BF16   (OFF_O3B_BYTES + 33554432ull)

__device__ __forceinline__ float bf2f(u16 h) {
  union { u32 u; float f; } v; v.u = ((u32)h) << 16; return v.f;
}
__device__ __forceinline__ u16 f2bf(float f) {
  union { float f; u32 u; } v; v.f = f;
  u32 r = (v.u + 0x7FFFu + ((v.u >> 16) & 1u)) >> 16;
  return (u16)r;
}

union BF8 { u16 u[8]; bf16x8 v; };

// ---------------- K0: M1P (bf16 packed), M2B, biask; zero s/bn --------------
__global__ __launch_bounds__(256) void k0_pre(
    const float* __restrict__ w1, const float* __restrict__ b1,
    const float* __restrict__ mk, const float* __restrict__ w2,
    float* __restrict__ W)
{
  u16* M1P = (u16*)((char*)W + OFF_M1P_BYTES);
  int g = blockIdx.x * 256 + threadIdx.x;
  if (g < 32768) {
    int k = g >> 8, c = g & 255;   // M1P[k][c] = sum_d w1[d,c]*mk[d,k]
    float s0 = 0.f, s1 = 0.f, s2 = 0.f, s3 = 0.f;
#pragma unroll 4
    for (int d = 0; d < 256; d += 4) {
      s0 = fmaf(w1[(d+0)*256 + c], mk[(d+0)*128 + k], s0);
      s1 = fmaf(w1[(d+1)*256 + c], mk[(d+1)*128 + k], s1);
      s2 = fmaf(w1[(d+2)*256 + c], mk[(d+2)*128 + k], s2);
      s3 = fmaf(w1[(d+3)*256 + c], mk[(d+3)*128 + k], s3);
    }
    M1P[g] = f2bf((s0 + s1) + (s2 + s3));
  } else if (g < 65536) {
    int g2 = g - 32768;
    int d = g2 >> 7, k = g2 & 127; // M2B[d][k] = sum_c w2[d,c]*mk[c,k]
    float s0 = 0.f, s1 = 0.f, s2 = 0.f, s3 = 0.f;
#pragma unroll 4
    for (int c = 0; c < 256; c += 4) {
      s0 = fmaf(w2[d*256 + c+0], mk[(c+0)*128 + k], s0);
      s1 = fmaf(w2[d*256 + c+1], mk[(c+1)*128 + k], s1);
      s2 = fmaf(w2[d*256 + c+2], mk[(c+2)*128 + k], s2);
      s3 = fmaf(w2[d*256 + c+3], mk[(c+3)*128 + k], s3);
    }
    W[OFF_M2B + g2] = (s0 + s1) + (s2 + s3);
  } else if (g < 65664) {
    int k = g - 65536;
    float s0 = 0.f, s1 = 0.f, s2 = 0.f, s3 = 0.f;
#pragma unroll 4
    for (int d = 0; d < 256; d += 4) {
      s0 = fmaf(b1[d+0], mk[(d+0)*128 + k], s0);
      s1 = fmaf(b1[d+1], mk[(d+1)*128 + k], s1);
      s2 = fmaf(b1[d+2], mk[(d+2)*128 + k], s2);
      s3 = fmaf(b1[d+3], mk[(d+3)*128 + k], s3);
    }
    W[OFF_BK + k] = (s0 + s1) + (s2 + s3);
  } else if (g < 65664 + 10240) {
    W[OFF_S + (g - 65664)] = 0.f;  // zero s[] and bnacc (contiguous)
  }
}

// ---------------- K1: p = exp(x^T @ M1 + biask); s[b][k] = sum_n p ---------
// v4: A = M1P (fully LDS-resident, XOR-swizzled), B = x direct from global
// (coalesced 16-token segments, 1-iter register prefetch). D = [k][token] ->
// ushort4 p stores. 128 tokens/block, grid (32,16) = 512 blocks = 2/CU.
// No global latency on the MFMA critical path.
__global__ __launch_bounds__(256, 2) void k1_logits(
    const float* __restrict__ x, float* __restrict__ W,
    u16* __restrict__ p)
{
  const u16* M1Pg = (const u16*)((char*)W + OFF_M1P_BYTES);
  const float* biask = W + OFF_BK;
  float* s_glob = W + OFF_S;

  __shared__ u16 m1s[32768];            // 64 KB: M1P swizzled; tail-reused for s_red

  const int tid  = threadIdx.x;
  const int wave = tid >> 6;
  const int lane = tid & 63;
  const int q    = lane >> 4;
  const int col  = lane & 15;
  const int b    = blockIdx.y;
  const int n_blk = blockIdx.x * 128;

  // ---- stage M1P[k][c] -> LDS, row-swizzled: byte ^= (k&7)<<4
#pragma unroll
  for (int it = 0; it < 16; ++it) {
    int ch = it * 256 + tid;            // 16B chunk id, [0,4096)
    int k = ch >> 5, c16 = ch & 31;
    uint4 v = *(const uint4*)(M1Pg + k * 256 + c16 * 8);
    u32 boff = (u32)(k * 512) + (((u32)(c16 * 16)) ^ (((u32)k & 7u) << 4));
    *(uint4*)((char*)m1s + boff) = v;
  }
  __syncthreads();

  f32x4 acc0[8], acc1[8];
#pragma unroll
  for (int t = 0; t < 8; ++t) {
    acc0[t] = (f32x4){0.f, 0.f, 0.f, 0.f};
    acc1[t] = (f32x4){0.f, 0.f, 0.f, 0.f};
  }

  // B-operand pointers: token = n_blk + wave*32 + {0,16} + col
  const float* xg0 = x + (size_t)b * CC * NN + n_blk + wave * 32 + col;
  const float* xg1 = xg0 + 16;

  float xl0[8], xl1[8], yl0[8], yl1[8];
#pragma unroll
  for (int j = 0; j < 8; ++j) {
    xl0[j] = xg0[(q * 8 + j) * NN];
    xl1[j] = xg1[(q * 8 + j) * NN];
  }

#pragma unroll
  for (int c0 = 0; c0 < 256; c0 += 32) {
    if (c0 < 224) {
#pragma unroll
      for (int j = 0; j < 8; ++j) {
        yl0[j] = xg0[(c0 + 32 + q * 8 + j) * NN];
        yl1[j] = xg1[(c0 + 32 + q * 8 + j) * NN];
      }
    }
    BF8 b0, b1;
#pragma unroll
    for (int j = 0; j < 8; ++j) { b0.u[j] = f2bf(xl0[j]); b1.u[j] = f2bf(xl1[j]); }
    const u32 acoff = ((u32)(c0 * 2 + q * 16)) ^ (((u32)col & 7u) << 4);
#pragma unroll
    for (int t = 0; t < 8; ++t) {
      bf16x8 a = *(const bf16x8*)((const char*)m1s + (u32)((t * 16 + col) * 512) + acoff);
      acc0[t] = __builtin_amdgcn_mfma_f32_16x16x32_bf16(a, b0.v, acc0[t], 0, 0, 0);
      acc1[t] = __builtin_amdgcn_mfma_f32_16x16x32_bf16(a, b1.v, acc1[t], 0, 0, 0);
    }
    if (c0 < 224) {
#pragma unroll
      for (int j = 0; j < 8; ++j) { xl0[j] = yl0[j]; xl1[j] = yl1[j]; }
    }
  }

  // ---- m1s is dead; reuse for the per-wave column-sum buffer
  __syncthreads();
  float* s_red = (float*)m1s;           // [4 waves][128 k]

  // epilogue: D[row = k-local = q*4+r][col = token]. bias, exp, ushort4 store.
  u16* pb = p + (size_t)b * NN * KK;
  const int tok0 = n_blk + wave * 32 + col;
#pragma unroll
  for (int t = 0; t < 8; ++t) {
    const float4 bk = *(const float4*)(biask + t * 16 + q * 4);
    u16 h0[4], h1[4];
    float sr[4];
#pragma unroll
    for (int r = 0; r < 4; ++r) {
      float e0 = __expf(acc0[t][r] + ((const float*)&bk)[r]);
      float e1 = __expf(acc1[t][r] + ((const float*)&bk)[r]);
      h0[r] = f2bf(e0); h1[r] = f2bf(e1);
      sr[r] = bf2f(h0[r]) + bf2f(h1[r]);   // rounded values for consistency
    }
    ushort4 pk0; pk0.x = h0[0]; pk0.y = h0[1]; pk0.z = h0[2]; pk0.w = h0[3];
    ushort4 pk1; pk1.x = h1[0]; pk1.y = h1[1]; pk1.z = h1[2]; pk1.w = h1[3];
    *(ushort4*)(pb + (size_t)tok0 * KK + t * 16 + q * 4) = pk0;
    *(ushort4*)(pb + (size_t)(tok0 + 16) * KK + t * 16 + q * 4) = pk1;
    // reduce over the 16 col-lanes (token sum for this wave's 32 tokens)
#pragma unroll
    for (int r = 0; r < 4; ++r) {
      sr[r] += __shfl_xor(sr[r], 1);
      sr[r] += __shfl_xor(sr[r], 2);
      sr[r] += __shfl_xor(sr[r], 4);
      sr[r] += __shfl_xor(sr[r], 8);
    }
    if (col == 0) {
      float4 sv; sv.x = sr[0]; sv.y = sr[1]; sv.z = sr[2]; sv.w = sr[3];
      *(float4*)(&s_red[wave * 128 + t * 16 + q * 4]) = sv;
    }
  }
  __syncthreads();
  if (tid < 128) {
    float tot = s_red[tid] + s_red[128 + tid] + s_red[256 + tid] + s_red[384 + tid];
    atomicAdd(&s_glob[b * 128 + tid], tot);
  }
}

// ---------------- K2: M2s[b][d][k] = M2B/s (bf16) --------------------------
// (rn rowsums fused into k3 since r4)
__global__ __launch_bounds__(256) void k2_prep(
    const u16* __restrict__ p, float* __restrict__ W)
{
  __shared__ float sinv[128];
  u16* M2s = (u16*)((char*)W + OFF_M2S_BYTES);
  const float* s_glob = W + OFF_S;
  const int tid = threadIdx.x;

  int g = blockIdx.x * 256 + tid;       // [0, 524288)
  int b = g >> 15;
  if (tid < 128) sinv[tid] = 1.0f / s_glob[b*128 + tid];
  __syncthreads();
  int rem = g & 32767;                  // d*128 + k
  M2s[g] = f2bf(W[OFF_M2B + rem] * sinv[g & 127]);
}

// ---------------- K3: o3 = (p @ M2s^T)*rn + b2 ; rn in-register; BN partials
// grid (64 n-tiles, 16 b), block 256 = 4 waves. Wave: 64 tokens x 64 d.
// rn[n] = 1/(1e-5 + sum_k p[n,k]/s[k]) computed during the k-loop (each wave
// redundantly for its 64 tokens) — kills k2's rn pass (17 MB p re-read).
template <bool O3BF>
__global__ __launch_bounds__(256, 4) void k3_attn(
    const u16* __restrict__ p, const float* __restrict__ b2,
    float* __restrict__ W, float* __restrict__ o3f, u16* __restrict__ o3b)
{
  const u16* M2s = (const u16*)((char*)W + OFF_M2S_BYTES);
  float* bnacc = W + OFF_BN;

  __shared__ float sinv_s[128];

  const int tid  = threadIdx.x;
  const int wave = tid >> 6;
  const int lane = tid & 63;
  const int q    = lane >> 4;
  const int col  = lane & 15;
  const int b    = blockIdx.y;
  const int n_base = blockIdx.x * 64;
  const int d_base = wave * 64;

  if (tid < 128) sinv_s[tid] = 1.0f / (W + OFF_S)[b*128 + tid];
  __syncthreads();

  f32x4 acc[4][4];
#pragma unroll
  for (int g = 0; g < 4; ++g)
#pragma unroll
    for (int t = 0; t < 4; ++t) acc[g][t] = (f32x4){0.f, 0.f, 0.f, 0.f};
  float racc[4] = {0.f, 0.f, 0.f, 0.f};

  const u16* pb0 = p + ((size_t)b * NN + n_base + col) * KK;
  const u16* m2b = M2s + ((size_t)b << 15) + (size_t)(d_base + col) * 128;

#pragma unroll
  for (int k0 = 0; k0 < 128; k0 += 32) {
    bf16x8 bfp[4], amv[4];
#pragma unroll
    for (int g = 0; g < 4; ++g)
      bfp[g] = *(const bf16x8*)(pb0 + (size_t)(g*16)*KK + k0 + q*8);
#pragma unroll
    for (int t = 0; t < 4; ++t)
      amv[t] = *(const bf16x8*)(m2b + (size_t)(t*16)*128 + k0 + q*8);
    // rowsum partial: this lane's 8 k-values for token n_base + g*16 + col
    const float4 sva = *(const float4*)(&sinv_s[k0 + q*8]);
    const float4 svb = *(const float4*)(&sinv_s[k0 + q*8 + 4]);
#pragma unroll
    for (int g = 0; g < 4; ++g) {
      racc[g] += (float)bfp[g][0] * sva.x + (float)bfp[g][1] * sva.y
               + (float)bfp[g][2] * sva.z + (float)bfp[g][3] * sva.w
               + (float)bfp[g][4] * svb.x + (float)bfp[g][5] * svb.y
               + (float)bfp[g][6] * svb.z + (float)bfp[g][7] * svb.w;
    }
#pragma unroll
    for (int g = 0; g < 4; ++g)
#pragma unroll
      for (int t = 0; t < 4; ++t)
        acc[g][t] = __builtin_amdgcn_mfma_f32_16x16x32_bf16(bfp[g], amv[t], acc[g][t], 0, 0, 0);
  }

  // finish rn per token: reduce over q-lanes, then redistribute to (q*4+r)
  float rn_g[4];
#pragma unroll
  for (int g = 0; g < 4; ++g) {
    float s = racc[g];
    s += __shfl_xor(s, 16);
    s += __shfl_xor(s, 32);
    rn_g[g] = 1.0f / (1e-5f + s);
  }
  const int src_base = (lane & 48) | ((lane & 48) >> 2);  // q*16 + q*4

  // epilogue: *rn + b2, token-contiguous stores, register-folded BN
  float* obf = o3f + (size_t)b * CC * NN;
  u16*   obb = o3b + (size_t)b * CC * NN;
  float s1t[4] = {0.f, 0.f, 0.f, 0.f};
  float s2t[4] = {0.f, 0.f, 0.f, 0.f};
#pragma unroll
  for (int g = 0; g < 4; ++g) {
    float rnr[4];
#pragma unroll
    for (int r = 0; r < 4; ++r) rnr[r] = __shfl(rn_g[g], src_base + r);
#pragma unroll
    for (int t = 0; t < 4; ++t) {
      const int d = d_base + t*16 + col;
      const float bb = b2[d];
      float4 vv;
      vv.x = fmaf(acc[g][t][0], rnr[0], bb);
      vv.y = fmaf(acc[g][t][1], rnr[1], bb);
      vv.z = fmaf(acc[g][t][2], rnr[2], bb);
      vv.w = fmaf(acc[g][t][3], rnr[3], bb);
      if (O3BF) {
        ushort4 pk;
        pk.x = f2bf(vv.x); pk.y = f2bf(vv.y); pk.z = f2bf(vv.z); pk.w = f2bf(vv.w);
        *(ushort4*)(obb + (size_t)d * NN + n_base + g*16 + q*4) = pk;
      } else {
        *(float4*)(obf + (size_t)d * NN + n_base + g*16 + q*4) = vv;
      }
      s1t[t] += vv.x + vv.y + vv.z + vv.w;
      s2t[t] += vv.x*vv.x + vv.y*vv.y + vv.z*vv.z + vv.w*vv.w;
    }
  }
  const int rep = blockIdx.x & 15;
#pragma unroll
  for (int t = 0; t < 4; ++t) {
    float s1 = s1t[t], s2 = s2t[t];
    s1 += __shfl_xor(s1, 16);  s2 += __shfl_xor(s2, 16);
    s1 += __shfl_xor(s1, 32);  s2 += __shfl_xor(s2, 32);
    if (lane < 16) {
      const int d = d_base + t*16 + col;
      atomicAdd(&bnacc[rep*512 + d], s1);
      atomicAdd(&bnacc[rep*512 + 256 + d], s2);
    }
  }
}

// ---------------- K4: finalize BN scale/shift ------------------------------
__global__ __launch_bounds__(256) void k4_fin(
    const float* __restrict__ gamma, const float* __restrict__ beta,
    float* __restrict__ W)
{
  const float* bnacc = W + OFF_BN;
  int d = threadIdx.x;
  float s1 = 0.f, s2 = 0.f;
#pragma unroll
  for (int r = 0; r < 16; ++r) { s1 += bnacc[r*512 + d]; s2 += bnacc[r*512 + 256 + d]; }
  const float invn = 1.0f / 65536.0f;
  float mean = s1 * invn;
  float var = s2 * invn - mean * mean;
  float sc = gamma[d] * rsqrtf(var + 1e-3f);
  W[OFF_SC + d] = sc;
  W[OFF_SH + d] = beta[d] - mean * sc;
}

// ---------------- K5 (fp32 o3 in d_out, in-place): BN+residual+LeakyReLU ---
__global__ __launch_bounds__(256) void k5_out_f32(
    const float* __restrict__ x, const float* __restrict__ W,
    float* __restrict__ out)
{
  const float* scale = W + OFF_SC;
  const float* shift = W + OFF_SH;
  size_t gid = ((size_t)blockIdx.x * 256 + threadIdx.x) * 4;
  const int d = (int)((gid >> 12) & 255);
  const float sc = scale[d], sh = shift[d];
  float4 o = *(const float4*)(out + gid);     // o3 stored in d_out (fp32)
  float4 xv = *(const float4*)(x + gid);
  float v0 = fmaf(o.x, sc, sh) + xv.x;
  float v1 = fmaf(o.y, sc, sh) + xv.y;
  float v2 = fmaf(o.z, sc, sh) + xv.z;
  float v3 = fmaf(o.w, sc, sh) + xv.w;
  v0 = (v0 >= 0.f) ? v0 : 0.2f * v0;
  v1 = (v1 >= 0.f) ? v1 : 0.2f * v1;
  v2 = (v2 >= 0.f) ? v2 : 0.2f * v2;
  v3 = (v3 >= 0.f) ? v3 : 0.2f * v3;
  float4 st; st.x = v0; st.y = v1; st.z = v2; st.w = v3;
  *(float4*)(out + gid) = st;
}

// ---------------- K5 (bf16 o3 in workspace): BN+residual+LeakyReLU ---------
__global__ __launch_bounds__(256) void k5_out_bf16(
    const float* __restrict__ x, const float* __restrict__ W,
    const u16* __restrict__ o3b, float* __restrict__ out)
{
  const float* scale = W + OFF_SC;
  const float* shift = W + OFF_SH;
  size_t gid = ((size_t)blockIdx.x * 256 + threadIdx.x) * 8;
  const int d = (int)((gid >> 12) & 255);
  const float sc = scale[d], sh = shift[d];
  uint4 ov = *(const uint4*)(o3b + gid);
  float4 xa = *(const float4*)(x + gid);
  float4 xb = *(const float4*)(x + gid + 4);
  float o0 = bf2f((u16)(ov.x & 0xffff)), o1 = bf2f((u16)(ov.x >> 16));
  float o2 = bf2f((u16)(ov.y & 0xffff)), o3 = bf2f((u16)(ov.y >> 16));
  float o4 = bf2f((u16)(ov.z & 0xffff)), o5 = bf2f((u16)(ov.z >> 16));
  float o6 = bf2f((u16)(ov.w & 0xffff)), o7 = bf2f((u16)(ov.w >> 16));
  float v0 = fmaf(o0, sc, sh) + xa.x;
  float v1 = fmaf(o1, sc, sh) + xa.y;
  float v2 = fmaf(o2, sc, sh) + xa.z;
  float v3 = fmaf(o3, sc, sh) + xa.w;
  float v4 = fmaf(o4, sc, sh) + xb.x;
  float v5 = fmaf(o5, sc, sh) + xb.y;
  float v6 = fmaf(o6, sc, sh) + xb.z;
  float v7 = fmaf(o7, sc, sh) + xb.w;
  v0 = (v0 >= 0.f) ? v0 : 0.2f * v0;
  v1 = (v1 >= 0.f) ? v1 : 0.2f * v1;
  v2 = (v2 >= 0.f) ? v2 : 0.2f * v2;
  v3 = (v3 >= 0.f) ? v3 : 0.2f * v3;
  v4 = (v4 >= 0.f) ? v4 : 0.2f * v4;
  v5 = (v5 >= 0.f) ? v5 : 0.2f * v5;
  v6 = (v6 >= 0.f) ? v6 : 0.2f * v6;
  v7 = (v7 >= 0.f) ? v7 : 0.2f * v7;
  float4 sa; sa.x = v0; sa.y = v1; sa.z = v2; sa.w = v3;
  float4 sb; sb.x = v4; sb.y = v5; sb.z = v6; sb.w = v7;
  *(float4*)(out + gid)     = sa;
  *(float4*)(out + gid + 4) = sb;
}

extern "C" void kernel_launch(void* const* d_in, const int* in_sizes, int n_in,
                              void* d_out, int out_size, void* d_ws, size_t ws_size,
                              hipStream_t stream)
{
  const float* x  = (const float*)d_in[0];
  const float* w1 = (const float*)d_in[1];
  const float* b1 = (const float*)d_in[2];
  const float* mk = (const float*)d_in[3];
  const float* w2 = (const float*)d_in[4];
  const float* b2 = (const float*)d_in[5];
  const float* gamma = (const float*)d_in[6];
  const float* beta  = (const float*)d_in[7];

  float* W = (float*)d_ws;
  u16* p = (u16*)((char*)d_ws + OFF_P_BYTES);  // exp(logits) bf16 [B][N][K]
  u16* o3b = (u16*)((char*)d_ws + OFF_O3B_BYTES);
  float* out = (float*)d_out;
  const bool bigws = ws_size >= WS_NEED_BF16;

  k0_pre<<<dim3(297), dim3(256), 0, stream>>>(w1, b1, mk, w2, W);
  k1_logits<<<dim3(32, 16), dim3(256), 0, stream>>>(x, W, p);
  k2_prep<<<dim3(2048), dim3(256), 0, stream>>>(p, W);
  if (bigws) {
    k3_attn<true><<<dim3(64, 16), dim3(256), 0, stream>>>(p, b2, W, out, o3b);
    k4_fin<<<dim3(1), dim3(256), 0, stream>>>(gamma, beta, W);
    k5_out_bf16<<<dim3(8192), dim3(256), 0, stream>>>(x, W, o3b, out);
  } else {
    k3_attn<false><<<dim3(64, 16), dim3(256), 0, stream>>>(p, b2, W, out, o3b);
    k4_fin<<<dim3(1), dim3(256), 0, stream>>>(gamma, beta, W);
    k5_out_f32<<<dim3(16384), dim3(256), 0, stream>>>(x, W, out);
  }
}